// Round 1
// baseline (556.864 us; speedup 1.0000x reference)
//
#include <hip/hip_runtime.h>

#define IN_NODE 128
#define OUT_NODE 64
#define OUT_EDGE 16
#define NHEAD 4
#define HN (NHEAD * OUT_NODE)  // 256
#define HE (NHEAD * OUT_EDGE)  // 64
#define LEAKY 0.01f

// ---------------- wsum[k] = sum_c W_fij[c][k]  (16x64 -> 64) ----------------
__global__ void prep_wsum(const float* __restrict__ W_fij, float* __restrict__ wsum) {
    int k = threadIdx.x;  // 64 threads
    float s = 0.f;
#pragma unroll
    for (int c = 0; c < 16; ++c) s += W_fij[c * 64 + k];
    wsum[k] = s;
}

// ---------------- C[M,N] = A[M,128] @ W[128,N] (+bias) ----------------------
// 64x64 tile per block, 256 threads, 4x4 micro-tile, K chunked by 64.
__global__ __launch_bounds__(256) void gemm_k128(
    const float* __restrict__ A, const float* __restrict__ W,
    const float* __restrict__ bias, float* __restrict__ C, int M, int N)
{
    __shared__ float As[64 * 68];   // padded: stride 68 -> 2-way max on reads
    __shared__ float Ws[64 * 64];
    const int t = threadIdx.x;
    const int rowBase = blockIdx.x * 64;
    const int colBase = blockIdx.y * 64;
    const int tr = (t >> 4) << 2;   // 0..60
    const int tc = (t & 15) << 2;   // 0..60
    float acc[4][4] = {};

    for (int kt = 0; kt < 128; kt += 64) {
#pragma unroll
        for (int i = 0; i < 4; ++i) {           // stage A: 64 rows x 64 k
            int f4 = t + i * 256;               // 0..1023
            int r = f4 >> 4;
            int kf = (f4 & 15) << 2;
            float4 v = {0.f, 0.f, 0.f, 0.f};
            int row = rowBase + r;
            if (row < M) v = *reinterpret_cast<const float4*>(A + (size_t)row * 128 + kt + kf);
            *reinterpret_cast<float4*>(As + r * 68 + kf) = v;
        }
#pragma unroll
        for (int i = 0; i < 4; ++i) {           // stage W: 64 k x 64 cols
            int f4 = t + i * 256;
            int k = f4 >> 4;
            int cf = (f4 & 15) << 2;
            float4 v = *reinterpret_cast<const float4*>(W + (size_t)(kt + k) * N + colBase + cf);
            *reinterpret_cast<float4*>(Ws + k * 64 + cf) = v;
        }
        __syncthreads();
#pragma unroll 8
        for (int k = 0; k < 64; ++k) {
            float4 b = *reinterpret_cast<const float4*>(Ws + k * 64 + tc);
            float a0 = As[(tr + 0) * 68 + k];
            float a1 = As[(tr + 1) * 68 + k];
            float a2 = As[(tr + 2) * 68 + k];
            float a3 = As[(tr + 3) * 68 + k];
            acc[0][0] = fmaf(a0, b.x, acc[0][0]);
            acc[0][1] = fmaf(a0, b.y, acc[0][1]);
            acc[0][2] = fmaf(a0, b.z, acc[0][2]);
            acc[0][3] = fmaf(a0, b.w, acc[0][3]);
            acc[1][0] = fmaf(a1, b.x, acc[1][0]);
            acc[1][1] = fmaf(a1, b.y, acc[1][1]);
            acc[1][2] = fmaf(a1, b.z, acc[1][2]);
            acc[1][3] = fmaf(a1, b.w, acc[1][3]);
            acc[2][0] = fmaf(a2, b.x, acc[2][0]);
            acc[2][1] = fmaf(a2, b.y, acc[2][1]);
            acc[2][2] = fmaf(a2, b.z, acc[2][2]);
            acc[2][3] = fmaf(a2, b.w, acc[2][3]);
            acc[3][0] = fmaf(a3, b.x, acc[3][0]);
            acc[3][1] = fmaf(a3, b.y, acc[3][1]);
            acc[3][2] = fmaf(a3, b.z, acc[3][2]);
            acc[3][3] = fmaf(a3, b.w, acc[3][3]);
        }
        __syncthreads();
    }

    float4 bv = {0.f, 0.f, 0.f, 0.f};
    if (bias) bv = *reinterpret_cast<const float4*>(bias + colBase + tc);
#pragma unroll
    for (int i = 0; i < 4; ++i) {
        int row = rowBase + tr + i;
        if (row < M) {
            float4 o = { acc[i][0] + bv.x, acc[i][1] + bv.y,
                         acc[i][2] + bv.z, acc[i][3] + bv.w };
            *reinterpret_cast<float4*>(C + (size_t)row * N + colBase + tc) = o;
        }
    }
}

// ---------------- per-edge logits -> exp -> denominator ---------------------
// One wave (64 lanes) per edge; lane = h*16+f over the H*OUT_EDGE features.
// Logits are tiny (|e| < ~1) so exp without segment-max is numerically safe.
__global__ __launch_bounds__(256) void edge_logits(
    const float* __restrict__ f_ni, const float* __restrict__ f_nj,
    const float* __restrict__ reward, const int* __restrict__ src,
    const int* __restrict__ dst, const float* __restrict__ wsum,
    const float* __restrict__ b_e, const float* __restrict__ attn,
    float* __restrict__ a_out, float* __restrict__ s_sum, int E)
{
    int gid = blockIdx.x * 256 + threadIdx.x;
    int e = gid >> 6;
    int lane = threadIdx.x & 63;
    if (e >= E) return;
    int sn = src[e], dn = dst[e];
    float r = reward[e];
    float v = f_ni[(size_t)sn * HE + lane] + f_nj[(size_t)dn * HE + lane]
            + r * wsum[lane] + b_e[lane];
    v = (v >= 0.f) ? v : LEAKY * v;
    v *= attn[lane];
    // sum within each 16-lane (head) group
    v += __shfl_xor(v, 8);
    v += __shfl_xor(v, 4);
    v += __shfl_xor(v, 2);
    v += __shfl_xor(v, 1);
    if ((lane & 15) == 0) {
        int h = lane >> 4;
        float av = __expf(v);
        a_out[(size_t)e * NHEAD + h] = av;
        atomicAdd(&s_sum[(size_t)dn * NHEAD + h], av);
    }
}

// ---------------- weighted aggregation (head-mean folded) -------------------
// One wave per edge; lane = output feature f. val = sum_h w_h * h_src[src,h,f]
__global__ __launch_bounds__(256) void aggregate(
    const float* __restrict__ h_src, const float* __restrict__ a_buf,
    const float* __restrict__ s_sum, const int* __restrict__ src,
    const int* __restrict__ dst, float* __restrict__ out_acc, int E)
{
    int gid = blockIdx.x * 256 + threadIdx.x;
    int e = gid >> 6;
    int lane = threadIdx.x & 63;
    if (e >= E) return;
    int sn = src[e], dn = dst[e];
    float w = 0.f;
    if (lane < NHEAD) {
        float sv = s_sum[(size_t)dn * NHEAD + lane];
        w = a_buf[(size_t)e * NHEAD + lane] / (sv > 0.f ? sv : 1.f);
    }
    float w0 = __shfl(w, 0);
    float w1 = __shfl(w, 1);
    float w2 = __shfl(w, 2);
    float w3 = __shfl(w, 3);
    const float* hs = h_src + (size_t)sn * HN;
    float val = w0 * hs[lane] + w1 * hs[64 + lane] + w2 * hs[128 + lane] + w3 * hs[192 + lane];
    atomicAdd(&out_acc[(size_t)dn * OUT_NODE + lane], val);
}

// ---------------- finalize: mean over heads + relu --------------------------
__global__ void finalize(float* __restrict__ out, int n) {
    int i = blockIdx.x * 256 + threadIdx.x;
    if (i < n) {
        float v = out[i] * 0.25f;
        out[i] = v > 0.f ? v : 0.f;
    }
}

extern "C" void kernel_launch(void* const* d_in, const int* in_sizes, int n_in,
                              void* d_out, int out_size, void* d_ws, size_t ws_size,
                              hipStream_t stream) {
    const float* nfeats    = (const float*)d_in[0];
    const float* dst_feats = (const float*)d_in[1];
    const float* reward    = (const float*)d_in[2];
    const int*   src       = (const int*)d_in[3];
    const int*   dst       = (const int*)d_in[4];
    const float* W_ns      = (const float*)d_in[5];
    const float* b_ns      = (const float*)d_in[6];
    const float* W_ni      = (const float*)d_in[7];
    const float* W_nj      = (const float*)d_in[8];
    const float* W_fij     = (const float*)d_in[9];
    const float* attn      = (const float*)d_in[10];
    const float* b_e       = (const float*)d_in[11];
    float* out = (float*)d_out;

    const int Ns = in_sizes[0] / IN_NODE;
    const int Nd = in_sizes[1] / IN_NODE;
    const int E  = in_sizes[2];

    char* ws = (char*)d_ws;
    float* f_ni  = (float*)ws;  ws += (size_t)Ns * HE * 4;
    float* f_nj  = (float*)ws;  ws += (size_t)Nd * HE * 4;
    float* h_src = (float*)ws;  ws += (size_t)Ns * HN * 4;
    float* a_buf = (float*)ws;  ws += (size_t)E * NHEAD * 4;
    float* s_sum = (float*)ws;  ws += (size_t)Nd * NHEAD * 4;
    float* wsum  = (float*)ws;  ws += HE * 4;

    hipMemsetAsync(s_sum, 0, (size_t)Nd * NHEAD * 4, stream);
    hipMemsetAsync(out, 0, (size_t)out_size * 4, stream);

    prep_wsum<<<1, 64, 0, stream>>>(W_fij, wsum);

    dim3 blk(256);
    gemm_k128<<<dim3((Ns + 63) / 64, 1), blk, 0, stream>>>(nfeats,    W_ni, nullptr, f_ni, Ns, HE);
    gemm_k128<<<dim3((Nd + 63) / 64, 1), blk, 0, stream>>>(dst_feats, W_nj, nullptr, f_nj, Nd, HE);
    gemm_k128<<<dim3((Ns + 63) / 64, 4), blk, 0, stream>>>(nfeats,    W_ns, b_ns,    h_src, Ns, HN);

    int eb = (E + 3) / 4;  // 4 edges (waves) per 256-thread block
    edge_logits<<<eb, 256, 0, stream>>>(f_ni, f_nj, reward, src, dst, wsum, b_e, attn,
                                        a_buf, s_sum, E);
    aggregate<<<eb, 256, 0, stream>>>(h_src, a_buf, s_sum, src, dst, out, E);
    finalize<<<(out_size + 255) / 256, 256, 0, stream>>>(out, out_size);
}

// Round 2
// 405.135 us; speedup vs baseline: 1.3745x; 1.3745x over previous
//
#include <hip/hip_runtime.h>

#define IN_NODE 128
#define OUT_NODE 64
#define OUT_EDGE 16
#define NHEAD 4
#define HN (NHEAD * OUT_NODE)  // 256
#define HE (NHEAD * OUT_EDGE)  // 64
#define LEAKY 0.01f

__device__ __forceinline__ float bf2f(unsigned short u) {
    union { unsigned u; float f; } v; v.u = ((unsigned)u) << 16; return v.f;
}
__device__ __forceinline__ unsigned short f2bf(float x) {
    union { float f; unsigned u; } v; v.f = x;
    unsigned r = v.u + 0x7FFF + ((v.u >> 16) & 1);   // RNE
    return (unsigned short)(r >> 16);
}

// ---------------- wsum[k] = sum_c W_fij[c][k]  (16x64 -> 64) ----------------
__global__ void prep_wsum(const float* __restrict__ W_fij, float* __restrict__ wsum) {
    int k = threadIdx.x;  // 64 threads
    float s = 0.f;
#pragma unroll
    for (int c = 0; c < 16; ++c) s += W_fij[c * 64 + k];
    wsum[k] = s;
}

// ---------------- C[M,N](bf16) = A[M,128] @ W[128,N] (+bias) ----------------
// 64x64 tile / 256 threads / 4x4 micro-tile. A staged TRANSPOSED in LDS so
// both fragments are ds_read_b128.
__global__ __launch_bounds__(256) void gemm_k128(
    const float* __restrict__ A, const float* __restrict__ W,
    const float* __restrict__ bias, unsigned short* __restrict__ C, int M, int N)
{
    __shared__ float At[64 * 68];   // [k][row], stride 68 (16B-aligned rows)
    __shared__ float Ws[64 * 64];   // [k][col]
    const int t = threadIdx.x;
    const int rowBase = blockIdx.x * 64;
    const int colBase = blockIdx.y * 64;
    const int tr = (t >> 4) << 2;
    const int tc = (t & 15) << 2;
    float acc[4][4] = {};

    for (int kt = 0; kt < 128; kt += 64) {
#pragma unroll
        for (int i = 0; i < 4; ++i) {           // stage A transposed
            int f4 = t + i * 256;
            int r = f4 >> 4;
            int kf = (f4 & 15) << 2;
            float4 v = {0.f, 0.f, 0.f, 0.f};
            int row = rowBase + r;
            if (row < M) v = *reinterpret_cast<const float4*>(A + (size_t)row * 128 + kt + kf);
            At[(kf + 0) * 68 + r] = v.x;
            At[(kf + 1) * 68 + r] = v.y;
            At[(kf + 2) * 68 + r] = v.z;
            At[(kf + 3) * 68 + r] = v.w;
        }
#pragma unroll
        for (int i = 0; i < 4; ++i) {           // stage W
            int f4 = t + i * 256;
            int k = f4 >> 4;
            int cf = (f4 & 15) << 2;
            float4 v = *reinterpret_cast<const float4*>(W + (size_t)(kt + k) * N + colBase + cf);
            *reinterpret_cast<float4*>(Ws + k * 64 + cf) = v;
        }
        __syncthreads();
#pragma unroll 8
        for (int k = 0; k < 64; ++k) {
            float4 b = *reinterpret_cast<const float4*>(Ws + k * 64 + tc);
            float4 a = *reinterpret_cast<const float4*>(At + k * 68 + tr);
            acc[0][0] = fmaf(a.x, b.x, acc[0][0]);
            acc[0][1] = fmaf(a.x, b.y, acc[0][1]);
            acc[0][2] = fmaf(a.x, b.z, acc[0][2]);
            acc[0][3] = fmaf(a.x, b.w, acc[0][3]);
            acc[1][0] = fmaf(a.y, b.x, acc[1][0]);
            acc[1][1] = fmaf(a.y, b.y, acc[1][1]);
            acc[1][2] = fmaf(a.y, b.z, acc[1][2]);
            acc[1][3] = fmaf(a.y, b.w, acc[1][3]);
            acc[2][0] = fmaf(a.z, b.x, acc[2][0]);
            acc[2][1] = fmaf(a.z, b.y, acc[2][1]);
            acc[2][2] = fmaf(a.z, b.z, acc[2][2]);
            acc[2][3] = fmaf(a.z, b.w, acc[2][3]);
            acc[3][0] = fmaf(a.w, b.x, acc[3][0]);
            acc[3][1] = fmaf(a.w, b.y, acc[3][1]);
            acc[3][2] = fmaf(a.w, b.z, acc[3][2]);
            acc[3][3] = fmaf(a.w, b.w, acc[3][3]);
        }
        __syncthreads();
    }

    float4 bv = {0.f, 0.f, 0.f, 0.f};
    if (bias) bv = *reinterpret_cast<const float4*>(bias + colBase + tc);
#pragma unroll
    for (int i = 0; i < 4; ++i) {
        int row = rowBase + tr + i;
        if (row < M) {
            ushort4 o = { f2bf(acc[i][0] + bv.x), f2bf(acc[i][1] + bv.y),
                          f2bf(acc[i][2] + bv.z), f2bf(acc[i][3] + bv.w) };
            *reinterpret_cast<ushort4*>(C + (size_t)row * N + colBase + tc) = o;
        }
    }
}

// ---------------- counting sort by dst: hist / scan / scatter ---------------
__global__ void hist_kernel(const int* __restrict__ dst, int* __restrict__ cnt, int E) {
    int i = blockIdx.x * 256 + threadIdx.x;
    if (i < E) atomicAdd(&cnt[dst[i]], 1);
}

// 1024 elems per block, 256 threads
__global__ __launch_bounds__(256) void scan1(const int* __restrict__ cnt,
                                             int* __restrict__ row_ptr,
                                             int* __restrict__ partials, int n) {
    __shared__ int sums[256];
    int tid = threadIdx.x;
    int base = blockIdx.x * 1024;
    int v[4]; int tsum = 0;
#pragma unroll
    for (int j = 0; j < 4; ++j) {
        int idx = base + tid * 4 + j;
        v[j] = (idx < n) ? cnt[idx] : 0;
        tsum += v[j];
    }
    sums[tid] = tsum;
    __syncthreads();
    for (int off = 1; off < 256; off <<= 1) {
        int x = (tid >= off) ? sums[tid - off] : 0;
        __syncthreads();
        sums[tid] += x;
        __syncthreads();
    }
    int run = sums[tid] - tsum;   // exclusive prefix for this thread
#pragma unroll
    for (int j = 0; j < 4; ++j) {
        int idx = base + tid * 4 + j;
        if (idx < n) row_ptr[idx] = run;
        run += v[j];
    }
    if (tid == 255) partials[blockIdx.x] = sums[255];
}

__global__ __launch_bounds__(256) void scan2(int* __restrict__ partials, int nb) {
    __shared__ int s[256];
    int tid = threadIdx.x;
    int orig = (tid < nb) ? partials[tid] : 0;
    s[tid] = orig;
    __syncthreads();
    for (int off = 1; off < 256; off <<= 1) {
        int x = (tid >= off) ? s[tid - off] : 0;
        __syncthreads();
        s[tid] += x;
        __syncthreads();
    }
    if (tid < nb) partials[tid] = s[tid] - orig;  // exclusive
}

__global__ void scan3(int* __restrict__ row_ptr, const int* __restrict__ partials,
                      int n, int E) {
    int i = blockIdx.x * 256 + threadIdx.x;
    if (i < n) row_ptr[i] += partials[i >> 10];
    if (i == 0) row_ptr[n] = E;
}

__global__ void scatter_kernel(const int* __restrict__ src, const int* __restrict__ dst,
                               const float* __restrict__ reward,
                               const int* __restrict__ row_ptr, int* __restrict__ cursor,
                               int* __restrict__ src_s, int* __restrict__ dst_s,
                               float* __restrict__ r_s, int E) {
    int i = blockIdx.x * 256 + threadIdx.x;
    if (i >= E) return;
    int d = dst[i];
    int pos = row_ptr[d] + atomicAdd(&cursor[d], 1);
    src_s[pos] = src[i];
    dst_s[pos] = d;
    r_s[pos] = reward[i];
}

// ---------------- per-edge logits -> exp (sorted order) ---------------------
// 16 lanes per edge; lane l covers features 4l..4l+3 (head h = l/4).
__global__ __launch_bounds__(256) void edge_logits(
    const unsigned short* __restrict__ f_ni, const unsigned short* __restrict__ f_nj,
    const int* __restrict__ src_s, const int* __restrict__ dst_s,
    const float* __restrict__ r_s, const float* __restrict__ wsum,
    const float* __restrict__ b_e, const float* __restrict__ attn,
    float* __restrict__ a_s, int E)
{
    int gid = blockIdx.x * 256 + threadIdx.x;
    int q = gid >> 4;
    if (q >= E) return;
    int l = threadIdx.x & 15;
    int sn = src_s[q], dn = dst_s[q];
    float r = r_s[q];
    ushort4 ui = *reinterpret_cast<const ushort4*>(f_ni + (size_t)sn * HE + 4 * l);
    ushort4 uj = *reinterpret_cast<const ushort4*>(f_nj + (size_t)dn * HE + 4 * l);
    float4 ws = *reinterpret_cast<const float4*>(wsum + 4 * l);
    float4 be = *reinterpret_cast<const float4*>(b_e + 4 * l);
    float4 at = *reinterpret_cast<const float4*>(attn + 4 * l);
    float t = 0.f, v;
    v = bf2f(ui.x) + bf2f(uj.x) + r * ws.x + be.x; v = (v >= 0.f) ? v : LEAKY * v; t += v * at.x;
    v = bf2f(ui.y) + bf2f(uj.y) + r * ws.y + be.y; v = (v >= 0.f) ? v : LEAKY * v; t += v * at.y;
    v = bf2f(ui.z) + bf2f(uj.z) + r * ws.z + be.z; v = (v >= 0.f) ? v : LEAKY * v; t += v * at.z;
    v = bf2f(ui.w) + bf2f(uj.w) + r * ws.w + be.w; v = (v >= 0.f) ? v : LEAKY * v; t += v * at.w;
    t += __shfl_xor(t, 1);
    t += __shfl_xor(t, 2);
    if ((l & 3) == 0) a_s[(size_t)q * NHEAD + (l >> 2)] = __expf(t);
}

// ---------------- aggregation: one wave per dst node, no atomics ------------
// lane = h*16+g; accumulates features [h][4g..4g+3]; reduce over heads at end.
__global__ __launch_bounds__(256) void aggregate(
    const unsigned short* __restrict__ h_src, const float* __restrict__ a_s,
    const int* __restrict__ src_s, const int* __restrict__ row_ptr,
    float* __restrict__ out, int Nd)
{
    int d = blockIdx.x * 4 + (threadIdx.x >> 6);
    if (d >= Nd) return;
    int lane = threadIdx.x & 63;
    int beg = row_ptr[d], end = row_ptr[d + 1];

    // softmax denominators (per head)
    float s = 0.f;
    for (int i = beg * 4 + lane; i < end * 4; i += 64) s += a_s[i];
    s += __shfl_xor(s, 4);
    s += __shfl_xor(s, 8);
    s += __shfl_xor(s, 16);
    s += __shfl_xor(s, 32);          // lane l now holds sum for head (l&3)
    int h = lane >> 4;
    float sh = __shfl(s, h);         // lane h holds head h's sum
    float inv = (sh > 0.f) ? 1.f / sh : 0.f;

    float a0 = 0.f, a1 = 0.f, a2 = 0.f, a3 = 0.f;
#pragma unroll 2
    for (int slot = beg; slot < end; ++slot) {
        int sn = src_s[slot];
        float w = a_s[(size_t)slot * NHEAD + h] * inv;
        ushort4 u = *reinterpret_cast<const ushort4*>(h_src + (size_t)sn * HN + lane * 4);
        a0 += w * bf2f(u.x);
        a1 += w * bf2f(u.y);
        a2 += w * bf2f(u.z);
        a3 += w * bf2f(u.w);
    }
    // reduce over heads (lanes g, 16+g, 32+g, 48+g)
    a0 += __shfl_xor(a0, 16); a0 += __shfl_xor(a0, 32);
    a1 += __shfl_xor(a1, 16); a1 += __shfl_xor(a1, 32);
    a2 += __shfl_xor(a2, 16); a2 += __shfl_xor(a2, 32);
    a3 += __shfl_xor(a3, 16); a3 += __shfl_xor(a3, 32);
    if (lane < 16) {
        float4 o = { fmaxf(a0 * 0.25f, 0.f), fmaxf(a1 * 0.25f, 0.f),
                     fmaxf(a2 * 0.25f, 0.f), fmaxf(a3 * 0.25f, 0.f) };
        *reinterpret_cast<float4*>(out + (size_t)d * OUT_NODE + lane * 4) = o;
    }
}

static inline char* align256(char* p) {
    return (char*)(((uintptr_t)p + 255) & ~(uintptr_t)255);
}

extern "C" void kernel_launch(void* const* d_in, const int* in_sizes, int n_in,
                              void* d_out, int out_size, void* d_ws, size_t ws_size,
                              hipStream_t stream) {
    const float* nfeats    = (const float*)d_in[0];
    const float* dst_feats = (const float*)d_in[1];
    const float* reward    = (const float*)d_in[2];
    const int*   src       = (const int*)d_in[3];
    const int*   dst       = (const int*)d_in[4];
    const float* W_ns      = (const float*)d_in[5];
    const float* b_ns      = (const float*)d_in[6];
    const float* W_ni      = (const float*)d_in[7];
    const float* W_nj      = (const float*)d_in[8];
    const float* W_fij     = (const float*)d_in[9];
    const float* attn      = (const float*)d_in[10];
    const float* b_e       = (const float*)d_in[11];
    float* out = (float*)d_out;

    const int Ns = in_sizes[0] / IN_NODE;
    const int Nd = in_sizes[1] / IN_NODE;
    const int E  = in_sizes[2];

    char* ws = (char*)d_ws;
    unsigned short* f_ni  = (unsigned short*)ws; ws = align256(ws + (size_t)Ns * HE * 2);
    unsigned short* f_nj  = (unsigned short*)ws; ws = align256(ws + (size_t)Nd * HE * 2);
    unsigned short* h_src = (unsigned short*)ws; ws = align256(ws + (size_t)Ns * HN * 2);
    float* wsum    = (float*)ws; ws = align256(ws + HE * 4);
    int*   cnt     = (int*)ws;   ws = align256(ws + (size_t)Nd * 4);
    int*   row_ptr = (int*)ws;   ws = align256(ws + (size_t)(Nd + 1) * 4);
    int*   cursor  = (int*)ws;   ws = align256(ws + (size_t)Nd * 4);
    int*   partials= (int*)ws;   ws = align256(ws + 256 * 4);
    int*   src_s   = (int*)ws;   ws = align256(ws + (size_t)E * 4);
    int*   dst_s   = (int*)ws;   ws = align256(ws + (size_t)E * 4);
    float* r_s     = (float*)ws; ws = align256(ws + (size_t)E * 4);
    float* a_s     = (float*)ws; ws = align256(ws + (size_t)E * NHEAD * 4);

    hipMemsetAsync(cnt, 0, (size_t)Nd * 4, stream);
    hipMemsetAsync(cursor, 0, (size_t)Nd * 4, stream);

    prep_wsum<<<1, 64, 0, stream>>>(W_fij, wsum);

    dim3 blk(256);
    gemm_k128<<<dim3((Ns + 63) / 64, 1), blk, 0, stream>>>(nfeats,    W_ni, nullptr, f_ni, Ns, HE);
    gemm_k128<<<dim3((Nd + 63) / 64, 1), blk, 0, stream>>>(dst_feats, W_nj, nullptr, f_nj, Nd, HE);
    gemm_k128<<<dim3((Ns + 63) / 64, 4), blk, 0, stream>>>(nfeats,    W_ns, b_ns,    h_src, Ns, HN);

    // counting sort by dst
    hist_kernel<<<(E + 255) / 256, 256, 0, stream>>>(dst, cnt, E);
    int nb = (Nd + 1023) / 1024;
    scan1<<<nb, 256, 0, stream>>>(cnt, row_ptr, partials, Nd);
    scan2<<<1, 256, 0, stream>>>(partials, nb);
    scan3<<<(Nd + 255) / 256, 256, 0, stream>>>(row_ptr, partials, Nd, E);
    scatter_kernel<<<(E + 255) / 256, 256, 0, stream>>>(src, dst, reward, row_ptr, cursor,
                                                        src_s, dst_s, r_s, E);

    // edge logits (16 lanes/edge)
    edge_logits<<<(int)(((size_t)E * 16 + 255) / 256), 256, 0, stream>>>(
        f_ni, f_nj, src_s, dst_s, r_s, wsum, b_e, attn, a_s, E);

    // aggregation (1 wave/dst)
    aggregate<<<(Nd + 3) / 4, 256, 0, stream>>>(h_src, a_s, src_s, row_ptr, out, Nd);
}